// Round 17
// baseline (46.826 us; speedup 1.0000x reference)
//
#include <hip/hip_runtime.h>

// MEASUREMENT ROUND: round-13 best kernel verbatim (30.74us), but vslideh is
// launched TWICE (idempotent: reads x,BP; writes identical out). The dur
// delta vs 30.74 isolates K2's true per-dispatch cost, which rocprof top-5
// hides (fill kernels dominate the table).
//
// Box filter 1024x1024 constant kernel, reflect pad (pl=pt=511, pr=pb=512).
// out = KC * H(V(x)) with V-first (linearity). 2-kernel pipeline:
//  K1 scanx: per (ch, 32-col slab) block (192 blocks): read x slab, form
//     4-row band sums in LDS, per-column shuffle scan -> BP4[ch][257][1024].
//  K2 vslideh: per (ch, 4-row band): vertical sliding recurrence on x gives
//     4 U rows in registers; rows H-transformed (hpass scan + hwindow,
//     double-buffered LDS, 2 syncs/row), *KC -> out.

static constexpr float KC = 2.5652997311834374e-21f;
#define IMG (1024 * 1024)

__device__ __forceinline__ float hwindow(const float* S, int o) {
    float r = 0.f;
    if (o <= 510) r += S[512 - o] - S[1];                 // left mirror
    const int b0 = o > 511 ? o - 511 : 0;                 // main
    const int b1 = o + 513 < 1024 ? o + 513 : 1024;
    r += S[b1] - S[b0];
    if (o >= 512) r += S[1023] - S[1534 - o];             // right mirror
    return r;
}

// hpass row body: scan u across the block, hwindow, write. No trailing sync
// (caller alternates S/wtot buffers).
__device__ __forceinline__ void hrow_emit(float4 u, float* S, float* wtot,
                                          float* orow, int t) {
    const float p0 = u.x, p1 = p0 + u.y, p2 = p1 + u.z, p3 = p2 + u.w;
    const int lane = t & 63, wave = t >> 6;
    float inc = p3;
    #pragma unroll
    for (int off = 1; off < 64; off <<= 1) {
        float n = __shfl_up(inc, off);
        if (lane >= off) inc += n;
    }
    if (lane == 63) wtot[wave] = inc;
    __syncthreads();
    float woff = 0.f;
    for (int w = 0; w < wave; ++w) woff += wtot[w];
    const float excl = woff + inc - p3;
    S[4 * t + 0] = excl;
    S[4 * t + 1] = excl + p0;
    S[4 * t + 2] = excl + p1;
    S[4 * t + 3] = excl + p2;
    if (t == 255) S[1024] = excl + p3;
    __syncthreads();
    float4 o;
    const int ox = 4 * t;
    o.x = KC * hwindow(S, ox + 0);
    o.y = KC * hwindow(S, ox + 1);
    o.z = KC * hwindow(S, ox + 2);
    o.w = KC * hwindow(S, ox + 3);
    reinterpret_cast<float4*>(orow)[t] = o;
}

// ---- K1: band sums from x + per-column scan -> BP4 ------------------------
// grid 192 = 6ch x 32 colslabs(32 cols), 256 threads
__global__ __launch_bounds__(256) void scanx_kernel(const float* __restrict__ x,
                                                    float* __restrict__ BP) {
    __shared__ float B[257][33];
    const int t = threadIdx.x;
    const int ch = blockIdx.x >> 5, cg = blockIdx.x & 31;
    const int col0 = cg * 32;
    const int c = t & 31, g = t >> 5;          // 8 row-groups of 32 lanes
    const float* xc = x + (size_t)ch * IMG + col0 + c;

    // 4-row band sums: thread (c,g) owns bands g, g+8, ..., g+248
    #pragma unroll 4
    for (int i = 0; i < 32; ++i) {
        const int band = g + 8 * i;
        const float* p = xc + (size_t)band * 4 * 1024;
        B[band][c] = (p[0] + p[1024]) + (p[2048] + p[3072]);
    }
    __syncthreads();

    // per-column scan over 256 bands (proven 4-segment body)
    const int lane = t & 63, wv = t >> 6;
    #pragma unroll
    for (int i = 0; i < 8; ++i) {
        const int cc = wv * 8 + i;
        float v0 = B[lane][cc], v1 = B[lane + 64][cc],
              v2 = B[lane + 128][cc], v3 = B[lane + 192][cc];
        float i0 = v0, i1 = v1, i2 = v2, i3 = v3;
        #pragma unroll
        for (int off = 1; off < 64; off <<= 1) {
            float n0 = __shfl_up(i0, off), n1 = __shfl_up(i1, off);
            float n2 = __shfl_up(i2, off), n3 = __shfl_up(i3, off);
            if (lane >= off) { i0 += n0; i1 += n1; i2 += n2; i3 += n3; }
        }
        const float t0 = __shfl(i0, 63), t1 = __shfl(i1, 63), t2 = __shfl(i2, 63);
        B[lane][cc]       = i0 - v0;
        B[lane + 64][cc]  = t0 + i1 - v1;
        B[lane + 128][cc] = t0 + t1 + i2 - v2;
        B[lane + 192][cc] = t0 + t1 + t2 + i3 - v3;
        if (lane == 63) B[256][cc] = t0 + t1 + t2 + i3;   // P[1024]
    }
    __syncthreads();

    // coalesced write-out of all 257 rows
    float* Bp = BP + (size_t)ch * 257 * 1024 + col0;
    #pragma unroll
    for (int i = 0; i < 33; ++i) {
        const int idx = i * 256 + t;
        if (idx < 257 * 32) {
            const int k = idx >> 5, cw = idx & 31;
            Bp[(size_t)k * 1024 + cw] = B[k][cw];
        }
    }
}

// ---- K2: vertical slide + in-block horizontal. grid 1536 = 6ch x 256 bands
__global__ __launch_bounds__(256) void vslideh_kernel(const float* __restrict__ x,
                                                      const float* __restrict__ BP,
                                                      float* __restrict__ out) {
    __shared__ float S[2][1025];
    __shared__ float wtot[2][4];
    const int t = threadIdx.x;
    const int ch = blockIdx.x >> 8, band = blockIdx.x & 255;
    const int O = band * 4;
    const float* xc = x + (size_t)ch * IMG;
    const float* Bc = BP + (size_t)ch * 257 * 1024;
    float* oc = out + (size_t)ch * IMG;

    #define LD4(base, row) (reinterpret_cast<const float4*>((base) + (size_t)(row) * 1024)[t])

    float4 acc;
    if (band < 128) {
        // init U[O] = P[512-O] - P[1] + P[O+513]
        const float4 bA = LD4(Bc, (512 - O) >> 2);
        const float4 x0 = LD4(xc, 0);
        const float4 bB = LD4(Bc, (512 + O) >> 2);
        const float4 xb = LD4(xc, O + 512);
        acc.x = bA.x - x0.x + bB.x + xb.x;
        acc.y = bA.y - x0.y + bB.y + xb.y;
        acc.z = bA.z - x0.z + bB.z + xb.z;
        acc.w = bA.w - x0.w + bB.w + xb.w;
        hrow_emit(acc, S[0], wtot[0], oc + (size_t)O * 1024, t);
        const int jmax = (band == 127) ? 3 : 4;
        for (int j = 1; j < jmax; ++j) {
            const int o = O + j;
            const float4 a = LD4(xc, o + 512);
            const float4 s = LD4(xc, 512 - o);
            acc.x += a.x - s.x; acc.y += a.y - s.y;
            acc.z += a.z - s.z; acc.w += a.w - s.w;
            hrow_emit(acc, S[j & 1], wtot[j & 1], oc + (size_t)o * 1024, t);
        }
        if (band == 127) {   // o = 511: U = P[1024]
            const float4 u = LD4(Bc, 256);
            hrow_emit(u, S[1], wtot[1], oc + (size_t)511 * 1024, t);
        }
    } else {
        // init U[O-1] = P[1024] - P[O-512] + P[1023] - P[1535-O]
        const float4 bt = LD4(Bc, 256);
        const float4 bA = LD4(Bc, (O - 512) >> 2);
        const float4 xm = LD4(xc, 1023);
        const float4 bB = LD4(Bc, (1536 - O) >> 2);
        const float4 xf = LD4(xc, 1535 - O);
        acc.x = bt.x - bA.x + (bt.x - xm.x) - (bB.x - xf.x);
        acc.y = bt.y - bA.y + (bt.y - xm.y) - (bB.y - xf.y);
        acc.z = bt.z - bA.z + (bt.z - xm.z) - (bB.z - xf.z);
        acc.w = bt.w - bA.w + (bt.w - xm.w) - (bB.w - xf.w);
        #pragma unroll
        for (int j = 0; j < 4; ++j) {
            const int o = O + j;
            const float4 a = LD4(xc, 1534 - o);
            const float4 s = LD4(xc, o - 512);
            acc.x += a.x - s.x; acc.y += a.y - s.y;
            acc.z += a.z - s.z; acc.w += a.w - s.w;
            hrow_emit(acc, S[j & 1], wtot[j & 1], oc + (size_t)o * 1024, t);
        }
    }
    #undef LD4
}

extern "C" void kernel_launch(void* const* d_in, const int* in_sizes, int n_in,
                              void* d_out, int out_size, void* d_ws, size_t ws_size,
                              hipStream_t stream) {
    const float* x = (const float*)d_in[2];
    float* out = (float*)d_out;
    float* BP = (float*)d_ws;                        // 6*257*1024 floats
    scanx_kernel<<<192, 256, 0, stream>>>(x, BP);
    vslideh_kernel<<<1536, 256, 0, stream>>>(x, BP, out);
    vslideh_kernel<<<1536, 256, 0, stream>>>(x, BP, out);  // measurement: 2nd
}

// Round 18
// 29.923 us; speedup vs baseline: 1.5649x; 1.5649x over previous
//
#include <hip/hip_runtime.h>

// Box filter 1024x1024 constant kernel, reflect pad (pl=pt=511, pr=pb=512).
// out = KC * H(V(x)) with V-first (linearity). 2-dispatch pipeline:
//  K1 scanx: per (ch, 32-col slab) block, NOW 512 threads + float4 loads
//     (R17 measurement: old 256-thread scalar version was ~14us, latency-
//     bound at <1 wave/SIMD with 128 scalar loads/thread). Forms 4-row band
//     sums in LDS, per-column shuffle scan (proven body, 8 waves x 4 cols) ->
//     BP4[ch][257][1024], BP4[k]=P[4k], BP4[256]=P[1024].
//  K2 vslideh (round-13 verbatim, ~15us ~= its streaming floor): per
//     (ch, 4-row band): vertical sliding recurrence on x gives 4 U rows in
//     registers; rows H-transformed in-block (hpass scan + hwindow,
//     double-buffered LDS, 2 syncs/row), *KC -> out.
//    U[o] = U[o-1] + x[o+512] - x[512-o]   (1 <= o <= 510)
//    U[511] = P[1024]
//    U[o] = U[o-1] - x[o-512] + x[1534-o]  (513 <= o <= 1023)

static constexpr float KC = 2.5652997311834374e-21f;
#define IMG (1024 * 1024)

__device__ __forceinline__ float hwindow(const float* S, int o) {
    float r = 0.f;
    if (o <= 510) r += S[512 - o] - S[1];                 // left mirror
    const int b0 = o > 511 ? o - 511 : 0;                 // main
    const int b1 = o + 513 < 1024 ? o + 513 : 1024;
    r += S[b1] - S[b0];
    if (o >= 512) r += S[1023] - S[1534 - o];             // right mirror
    return r;
}

// hpass row body: scan u across the block, hwindow, write. No trailing sync
// (caller alternates S/wtot buffers).
__device__ __forceinline__ void hrow_emit(float4 u, float* S, float* wtot,
                                          float* orow, int t) {
    const float p0 = u.x, p1 = p0 + u.y, p2 = p1 + u.z, p3 = p2 + u.w;
    const int lane = t & 63, wave = t >> 6;
    float inc = p3;
    #pragma unroll
    for (int off = 1; off < 64; off <<= 1) {
        float n = __shfl_up(inc, off);
        if (lane >= off) inc += n;
    }
    if (lane == 63) wtot[wave] = inc;
    __syncthreads();
    float woff = 0.f;
    for (int w = 0; w < wave; ++w) woff += wtot[w];
    const float excl = woff + inc - p3;
    S[4 * t + 0] = excl;
    S[4 * t + 1] = excl + p0;
    S[4 * t + 2] = excl + p1;
    S[4 * t + 3] = excl + p2;
    if (t == 255) S[1024] = excl + p3;
    __syncthreads();
    float4 o;
    const int ox = 4 * t;
    o.x = KC * hwindow(S, ox + 0);
    o.y = KC * hwindow(S, ox + 1);
    o.z = KC * hwindow(S, ox + 2);
    o.w = KC * hwindow(S, ox + 3);
    reinterpret_cast<float4*>(orow)[t] = o;
}

// ---- K1: band sums from x + per-column scan -> BP4 ------------------------
// grid 192 = 6ch x 32 colslabs(32 cols), 512 threads, float4 loads
__global__ __launch_bounds__(512) void scanx_kernel(const float* __restrict__ x,
                                                    float* __restrict__ BP) {
    __shared__ float B[257][33];
    const int t = threadIdx.x;
    const int ch = blockIdx.x >> 5, cg = blockIdx.x & 31;
    const int col0 = cg * 32;
    const int c4 = t & 7, g = t >> 3;          // c4: float4-col [0,8), g: row-group [0,64)
    const float4* xc = reinterpret_cast<const float4*>(x + (size_t)ch * IMG + col0) + c4;
    // row stride = 256 float4

    // 4-row band sums: thread (c4,g) owns bands g, g+64, g+128, g+192
    #pragma unroll
    for (int i = 0; i < 4; ++i) {
        const int band = g + 64 * i;
        const float4* p = xc + (size_t)band * 4 * 256;
        const float4 r0 = p[0], r1 = p[256], r2 = p[512], r3 = p[768];
        const int cc = 4 * c4;
        B[band][cc + 0] = (r0.x + r1.x) + (r2.x + r3.x);
        B[band][cc + 1] = (r0.y + r1.y) + (r2.y + r3.y);
        B[band][cc + 2] = (r0.z + r1.z) + (r2.z + r3.z);
        B[band][cc + 3] = (r0.w + r1.w) + (r2.w + r3.w);
    }
    __syncthreads();

    // per-column scan over 256 bands (proven 4-segment body), 8 waves x 4 cols
    const int lane = t & 63, wv = t >> 6;
    #pragma unroll
    for (int i = 0; i < 4; ++i) {
        const int cc = wv * 4 + i;
        float v0 = B[lane][cc], v1 = B[lane + 64][cc],
              v2 = B[lane + 128][cc], v3 = B[lane + 192][cc];
        float i0 = v0, i1 = v1, i2 = v2, i3 = v3;
        #pragma unroll
        for (int off = 1; off < 64; off <<= 1) {
            float n0 = __shfl_up(i0, off), n1 = __shfl_up(i1, off);
            float n2 = __shfl_up(i2, off), n3 = __shfl_up(i3, off);
            if (lane >= off) { i0 += n0; i1 += n1; i2 += n2; i3 += n3; }
        }
        const float t0 = __shfl(i0, 63), t1 = __shfl(i1, 63), t2 = __shfl(i2, 63);
        B[lane][cc]       = i0 - v0;
        B[lane + 64][cc]  = t0 + i1 - v1;
        B[lane + 128][cc] = t0 + t1 + i2 - v2;
        B[lane + 192][cc] = t0 + t1 + t2 + i3 - v3;
        if (lane == 63) B[256][cc] = t0 + t1 + t2 + i3;   // P[1024]
    }
    __syncthreads();

    // coalesced write-out of all 257 rows
    float* Bp = BP + (size_t)ch * 257 * 1024 + col0;
    #pragma unroll
    for (int i = 0; i < 17; ++i) {
        const int idx = i * 512 + t;
        if (idx < 257 * 32) {
            const int k = idx >> 5, cw = idx & 31;
            Bp[(size_t)k * 1024 + cw] = B[k][cw];
        }
    }
}

// ---- K2: vertical slide + in-block horizontal. grid 1536 = 6ch x 256 bands
__global__ __launch_bounds__(256) void vslideh_kernel(const float* __restrict__ x,
                                                      const float* __restrict__ BP,
                                                      float* __restrict__ out) {
    __shared__ float S[2][1025];
    __shared__ float wtot[2][4];
    const int t = threadIdx.x;
    const int ch = blockIdx.x >> 8, band = blockIdx.x & 255;
    const int O = band * 4;
    const float* xc = x + (size_t)ch * IMG;
    const float* Bc = BP + (size_t)ch * 257 * 1024;
    float* oc = out + (size_t)ch * IMG;

    #define LD4(base, row) (reinterpret_cast<const float4*>((base) + (size_t)(row) * 1024)[t])

    float4 acc;
    if (band < 128) {
        // init U[O] = P[512-O] - P[1] + P[O+513]
        const float4 bA = LD4(Bc, (512 - O) >> 2);
        const float4 x0 = LD4(xc, 0);
        const float4 bB = LD4(Bc, (512 + O) >> 2);
        const float4 xb = LD4(xc, O + 512);
        acc.x = bA.x - x0.x + bB.x + xb.x;
        acc.y = bA.y - x0.y + bB.y + xb.y;
        acc.z = bA.z - x0.z + bB.z + xb.z;
        acc.w = bA.w - x0.w + bB.w + xb.w;
        hrow_emit(acc, S[0], wtot[0], oc + (size_t)O * 1024, t);
        const int jmax = (band == 127) ? 3 : 4;
        for (int j = 1; j < jmax; ++j) {
            const int o = O + j;
            const float4 a = LD4(xc, o + 512);
            const float4 s = LD4(xc, 512 - o);
            acc.x += a.x - s.x; acc.y += a.y - s.y;
            acc.z += a.z - s.z; acc.w += a.w - s.w;
            hrow_emit(acc, S[j & 1], wtot[j & 1], oc + (size_t)o * 1024, t);
        }
        if (band == 127) {   // o = 511: U = P[1024]
            const float4 u = LD4(Bc, 256);
            hrow_emit(u, S[1], wtot[1], oc + (size_t)511 * 1024, t);
        }
    } else {
        // init U[O-1] = P[1024] - P[O-512] + P[1023] - P[1535-O]
        const float4 bt = LD4(Bc, 256);
        const float4 bA = LD4(Bc, (O - 512) >> 2);
        const float4 xm = LD4(xc, 1023);
        const float4 bB = LD4(Bc, (1536 - O) >> 2);
        const float4 xf = LD4(xc, 1535 - O);
        acc.x = bt.x - bA.x + (bt.x - xm.x) - (bB.x - xf.x);
        acc.y = bt.y - bA.y + (bt.y - xm.y) - (bB.y - xf.y);
        acc.z = bt.z - bA.z + (bt.z - xm.z) - (bB.z - xf.z);
        acc.w = bt.w - bA.w + (bt.w - xm.w) - (bB.w - xf.w);
        #pragma unroll
        for (int j = 0; j < 4; ++j) {
            const int o = O + j;
            const float4 a = LD4(xc, 1534 - o);
            const float4 s = LD4(xc, o - 512);
            acc.x += a.x - s.x; acc.y += a.y - s.y;
            acc.z += a.z - s.z; acc.w += a.w - s.w;
            hrow_emit(acc, S[j & 1], wtot[j & 1], oc + (size_t)o * 1024, t);
        }
    }
    #undef LD4
}

extern "C" void kernel_launch(void* const* d_in, const int* in_sizes, int n_in,
                              void* d_out, int out_size, void* d_ws, size_t ws_size,
                              hipStream_t stream) {
    const float* x = (const float*)d_in[2];
    float* out = (float*)d_out;
    float* BP = (float*)d_ws;                        // 6*257*1024 floats
    scanx_kernel<<<192, 512, 0, stream>>>(x, BP);
    vslideh_kernel<<<1536, 256, 0, stream>>>(x, BP, out);
}

// Round 19
// 29.528 us; speedup vs baseline: 1.5858x; 1.0134x over previous
//
#include <hip/hip_runtime.h>

// Box filter 1024x1024 constant kernel, reflect pad (pl=pt=511, pr=pb=512).
// out = KC * H(V(x)) with V-first (linearity). 2-dispatch pipeline:
//  K1 scanx (R18): 192 blocks x 512 threads, float4 loads; 4-row band sums
//     in LDS + per-column shuffle scan -> BP4[ch][257][1024].
//  K2 vslideh (NEW: batched rows, 2 barriers/block instead of 8): per
//     (ch, 4-row band): vertical sliding recurrence gives u0..u3 in registers
//     (R14-proven construction); then ONE batched H-transform:
//       phase A: 4 interleaved block-scans (4x shfl ILP) -> wtot, sync
//       phase B: woff + write S[4][1025], sync
//       phase C: hwindow + float4 stores for all 4 rows
//     Values and order identical to R13 -> absmax bit-identical.
//    U[o] = U[o-1] + x[o+512] - x[512-o]   (1 <= o <= 510)
//    U[511] = P[1024]
//    U[o] = U[o-1] - x[o-512] + x[1534-o]  (513 <= o <= 1023)

static constexpr float KC = 2.5652997311834374e-21f;
#define IMG (1024 * 1024)

__device__ __forceinline__ float hwindow(const float* S, int o) {
    float r = 0.f;
    if (o <= 510) r += S[512 - o] - S[1];                 // left mirror
    const int b0 = o > 511 ? o - 511 : 0;                 // main
    const int b1 = o + 513 < 1024 ? o + 513 : 1024;
    r += S[b1] - S[b0];
    if (o >= 512) r += S[1023] - S[1534 - o];             // right mirror
    return r;
}

// ---- K1: band sums from x + per-column scan -> BP4 (R18 verbatim) ---------
// grid 192 = 6ch x 32 colslabs(32 cols), 512 threads, float4 loads
__global__ __launch_bounds__(512) void scanx_kernel(const float* __restrict__ x,
                                                    float* __restrict__ BP) {
    __shared__ float B[257][33];
    const int t = threadIdx.x;
    const int ch = blockIdx.x >> 5, cg = blockIdx.x & 31;
    const int col0 = cg * 32;
    const int c4 = t & 7, g = t >> 3;          // c4: float4-col [0,8), g: row-group [0,64)
    const float4* xc = reinterpret_cast<const float4*>(x + (size_t)ch * IMG + col0) + c4;

    #pragma unroll
    for (int i = 0; i < 4; ++i) {
        const int band = g + 64 * i;
        const float4* p = xc + (size_t)band * 4 * 256;
        const float4 r0 = p[0], r1 = p[256], r2 = p[512], r3 = p[768];
        const int cc = 4 * c4;
        B[band][cc + 0] = (r0.x + r1.x) + (r2.x + r3.x);
        B[band][cc + 1] = (r0.y + r1.y) + (r2.y + r3.y);
        B[band][cc + 2] = (r0.z + r1.z) + (r2.z + r3.z);
        B[band][cc + 3] = (r0.w + r1.w) + (r2.w + r3.w);
    }
    __syncthreads();

    const int lane = t & 63, wv = t >> 6;
    #pragma unroll
    for (int i = 0; i < 4; ++i) {
        const int cc = wv * 4 + i;
        float v0 = B[lane][cc], v1 = B[lane + 64][cc],
              v2 = B[lane + 128][cc], v3 = B[lane + 192][cc];
        float i0 = v0, i1 = v1, i2 = v2, i3 = v3;
        #pragma unroll
        for (int off = 1; off < 64; off <<= 1) {
            float n0 = __shfl_up(i0, off), n1 = __shfl_up(i1, off);
            float n2 = __shfl_up(i2, off), n3 = __shfl_up(i3, off);
            if (lane >= off) { i0 += n0; i1 += n1; i2 += n2; i3 += n3; }
        }
        const float t0 = __shfl(i0, 63), t1 = __shfl(i1, 63), t2 = __shfl(i2, 63);
        B[lane][cc]       = i0 - v0;
        B[lane + 64][cc]  = t0 + i1 - v1;
        B[lane + 128][cc] = t0 + t1 + i2 - v2;
        B[lane + 192][cc] = t0 + t1 + t2 + i3 - v3;
        if (lane == 63) B[256][cc] = t0 + t1 + t2 + i3;   // P[1024]
    }
    __syncthreads();

    float* Bp = BP + (size_t)ch * 257 * 1024 + col0;
    #pragma unroll
    for (int i = 0; i < 17; ++i) {
        const int idx = i * 512 + t;
        if (idx < 257 * 32) {
            const int k = idx >> 5, cw = idx & 31;
            Bp[(size_t)k * 1024 + cw] = B[k][cw];
        }
    }
}

// ---- K2: vertical slide + batched in-block horizontal. grid 1536 ----------
__global__ __launch_bounds__(256) void vslideh_kernel(const float* __restrict__ x,
                                                      const float* __restrict__ BP,
                                                      float* __restrict__ out) {
    __shared__ float S[4][1025];
    __shared__ float wtot[4][4];
    const int t = threadIdx.x;
    const int ch = blockIdx.x >> 8, band = blockIdx.x & 255;
    const int O = band * 4;
    const float* xc = x + (size_t)ch * IMG;
    const float* Bc = BP + (size_t)ch * 257 * 1024;
    float* oc = out + (size_t)ch * IMG;

    #define LD4(base, row) (reinterpret_cast<const float4*>((base) + (size_t)(row) * 1024)[t])

    // ---- u0..u3 (R14-proven construction) ----
    float4 u0, u1, u2, u3;
    if (band < 128) {
        const float4 bA = LD4(Bc, (512 - O) >> 2);
        const float4 x0 = LD4(xc, 0);
        const float4 bB = LD4(Bc, (512 + O) >> 2);
        const float4 xb = LD4(xc, O + 512);
        u0.x = bA.x - x0.x + bB.x + xb.x;
        u0.y = bA.y - x0.y + bB.y + xb.y;
        u0.z = bA.z - x0.z + bB.z + xb.z;
        u0.w = bA.w - x0.w + bB.w + xb.w;
        {
            const float4 a = LD4(xc, O + 513), s = LD4(xc, 511 - O);
            u1.x = u0.x + a.x - s.x; u1.y = u0.y + a.y - s.y;
            u1.z = u0.z + a.z - s.z; u1.w = u0.w + a.w - s.w;
        }
        {
            const float4 a = LD4(xc, O + 514), s = LD4(xc, 510 - O);
            u2.x = u1.x + a.x - s.x; u2.y = u1.y + a.y - s.y;
            u2.z = u1.z + a.z - s.z; u2.w = u1.w + a.w - s.w;
        }
        if (band == 127) {
            u3 = LD4(Bc, 256);                       // U[511] = P[1024]
        } else {
            const float4 a = LD4(xc, O + 515), s = LD4(xc, 509 - O);
            u3.x = u2.x + a.x - s.x; u3.y = u2.y + a.y - s.y;
            u3.z = u2.z + a.z - s.z; u3.w = u2.w + a.w - s.w;
        }
    } else {
        const float4 bt = LD4(Bc, 256);
        const float4 bA = LD4(Bc, (O - 512) >> 2);
        const float4 xm = LD4(xc, 1023);
        const float4 bB = LD4(Bc, (1536 - O) >> 2);
        const float4 xf = LD4(xc, 1535 - O);
        float4 acc;
        acc.x = bt.x - bA.x + (bt.x - xm.x) - (bB.x - xf.x);
        acc.y = bt.y - bA.y + (bt.y - xm.y) - (bB.y - xf.y);
        acc.z = bt.z - bA.z + (bt.z - xm.z) - (bB.z - xf.z);
        acc.w = bt.w - bA.w + (bt.w - xm.w) - (bB.w - xf.w);
        {
            const float4 a = LD4(xc, 1534 - O), s = LD4(xc, O - 512);
            u0.x = acc.x + a.x - s.x; u0.y = acc.y + a.y - s.y;
            u0.z = acc.z + a.z - s.z; u0.w = acc.w + a.w - s.w;
        }
        {
            const float4 a = LD4(xc, 1533 - O), s = LD4(xc, O - 511);
            u1.x = u0.x + a.x - s.x; u1.y = u0.y + a.y - s.y;
            u1.z = u0.z + a.z - s.z; u1.w = u0.w + a.w - s.w;
        }
        {
            const float4 a = LD4(xc, 1532 - O), s = LD4(xc, O - 510);
            u2.x = u1.x + a.x - s.x; u2.y = u1.y + a.y - s.y;
            u2.z = u1.z + a.z - s.z; u2.w = u1.w + a.w - s.w;
        }
        {
            const float4 a = LD4(xc, 1531 - O), s = LD4(xc, O - 509);
            u3.x = u2.x + a.x - s.x; u3.y = u2.y + a.y - s.y;
            u3.z = u2.z + a.z - s.z; u3.w = u2.w + a.w - s.w;
        }
    }
    #undef LD4

    const int lane = t & 63, wave = t >> 6;

    // ---- phase A: 4 interleaved block scans ----
    const float a0 = u0.x, a1 = a0 + u0.y, a2 = a1 + u0.z, a3 = a2 + u0.w;
    const float b0 = u1.x, b1 = b0 + u1.y, b2 = b1 + u1.z, b3 = b2 + u1.w;
    const float c0 = u2.x, c1 = c0 + u2.y, c2 = c1 + u2.z, c3 = c2 + u2.w;
    const float d0 = u3.x, d1 = d0 + u3.y, d2 = d1 + u3.z, d3 = d2 + u3.w;
    float iA = a3, iB = b3, iC = c3, iD = d3;
    #pragma unroll
    for (int off = 1; off < 64; off <<= 1) {
        float nA = __shfl_up(iA, off), nB = __shfl_up(iB, off);
        float nC = __shfl_up(iC, off), nD = __shfl_up(iD, off);
        if (lane >= off) { iA += nA; iB += nB; iC += nC; iD += nD; }
    }
    if (lane == 63) {
        wtot[0][wave] = iA; wtot[1][wave] = iB;
        wtot[2][wave] = iC; wtot[3][wave] = iD;
    }
    __syncthreads();

    // ---- phase B: bases + S writes for all 4 rows ----
    float wA = 0.f, wB = 0.f, wC = 0.f, wD = 0.f;
    for (int w = 0; w < wave; ++w) {
        wA += wtot[0][w]; wB += wtot[1][w];
        wC += wtot[2][w]; wD += wtot[3][w];
    }
    const float eA = wA + iA - a3;
    const float eB = wB + iB - b3;
    const float eC = wC + iC - c3;
    const float eD = wD + iD - d3;
    S[0][4 * t + 0] = eA;      S[0][4 * t + 1] = eA + a0;
    S[0][4 * t + 2] = eA + a1; S[0][4 * t + 3] = eA + a2;
    S[1][4 * t + 0] = eB;      S[1][4 * t + 1] = eB + b0;
    S[1][4 * t + 2] = eB + b1; S[1][4 * t + 3] = eB + b2;
    S[2][4 * t + 0] = eC;      S[2][4 * t + 1] = eC + c0;
    S[2][4 * t + 2] = eC + c1; S[2][4 * t + 3] = eC + c2;
    S[3][4 * t + 0] = eD;      S[3][4 * t + 1] = eD + d0;
    S[3][4 * t + 2] = eD + d1; S[3][4 * t + 3] = eD + d2;
    if (t == 255) {
        S[0][1024] = eA + a3; S[1][1024] = eB + b3;
        S[2][1024] = eC + c3; S[3][1024] = eD + d3;
    }
    __syncthreads();

    // ---- phase C: hwindow + stores for all 4 rows ----
    const int ox = 4 * t;
    #pragma unroll
    for (int j = 0; j < 4; ++j) {
        float4 o;
        o.x = KC * hwindow(S[j], ox + 0);
        o.y = KC * hwindow(S[j], ox + 1);
        o.z = KC * hwindow(S[j], ox + 2);
        o.w = KC * hwindow(S[j], ox + 3);
        reinterpret_cast<float4*>(oc + (size_t)(O + j) * 1024)[t] = o;
    }
}

extern "C" void kernel_launch(void* const* d_in, const int* in_sizes, int n_in,
                              void* d_out, int out_size, void* d_ws, size_t ws_size,
                              hipStream_t stream) {
    const float* x = (const float*)d_in[2];
    float* out = (float*)d_out;
    float* BP = (float*)d_ws;                        // 6*257*1024 floats
    scanx_kernel<<<192, 512, 0, stream>>>(x, BP);
    vslideh_kernel<<<1536, 256, 0, stream>>>(x, BP, out);
}